// Round 2
// baseline (773.954 us; speedup 1.0000x reference)
//
#include <hip/hip_runtime.h>

#define H_ 128
#define W_ 160
#define C_ 32
#define D_ 64
#define HW_ (H_*W_)          // 20480
#define DHW_ (D_*HW_)        // 1310720

// var/conv tile
#define TY 16
#define TX 16
#define HS 18                // halo side (TY+2)
#define NP_ (HS*HS)          // 324 halo positions

// ws layout (floats)
#define FEATT_SZ (5*HW_*C_)          // 3,276,800
#define MATS_OFF FEATT_SZ
#define CW2_OFF (MATS_OFF + 64)
#define A_OFF (CW2_OFF + 960)
// total floats = A_OFF + 3*DHW_ ~= 7,209,984 (~28.8 MB)

// ---------------------------------------------------------------- setup: mats + weight rearrange
__global__ void k_setup(const float* __restrict__ proj,
                        const float* __restrict__ convw,
                        float* __restrict__ mats,
                        float* __restrict__ cw2)
{
    const int tid = threadIdx.x;
    // rearrange conv weights: cw2[tap][c][kd] <- convw[c][kd][ky][kx], tap=ky*3+kx
    for (int i = tid; i < 864; i += 64) {
        const int tap = i / 96;
        const int rem = i - tap*96;
        const int c   = rem / 3;
        const int kd  = rem - c*3;
        cw2[i] = convw[c*27 + kd*9 + tap];
    }
    if (tid != 0) return;
    double F[5][12];
    for (int v = 0; v < 5; ++v) {
        const float* E = proj + v*32;
        const float* K = proj + v*32 + 16;
        for (int i = 0; i < 3; ++i)
            for (int j = 0; j < 4; ++j) {
                double s = 0.0;
                for (int k = 0; k < 3; ++k)
                    s += (double)K[i*4+k] * (double)E[k*4+j];
                F[v][i*4+j] = s;
            }
    }
    const double m00=F[0][0], m01=F[0][1], m02=F[0][2],  t0x=F[0][3];
    const double m10=F[0][4], m11=F[0][5], m12=F[0][6],  t0y=F[0][7];
    const double m20=F[0][8], m21=F[0][9], m22=F[0][10], t0z=F[0][11];
    const double det = m00*(m11*m22-m12*m21) - m01*(m10*m22-m12*m20)
                     + m02*(m10*m21-m11*m20);
    const double id = 1.0/det;
    double inv[9];
    inv[0] = (m11*m22-m12*m21)*id; inv[1] = (m02*m21-m01*m22)*id; inv[2] = (m01*m12-m02*m11)*id;
    inv[3] = (m12*m20-m10*m22)*id; inv[4] = (m00*m22-m02*m20)*id; inv[5] = (m02*m10-m00*m12)*id;
    inv[6] = (m10*m21-m11*m20)*id; inv[7] = (m01*m20-m00*m21)*id; inv[8] = (m00*m11-m01*m10)*id;
    double it[3];
    it[0] = -(inv[0]*t0x + inv[1]*t0y + inv[2]*t0z);
    it[1] = -(inv[3]*t0x + inv[4]*t0y + inv[5]*t0z);
    it[2] = -(inv[6]*t0x + inv[7]*t0y + inv[8]*t0z);
    for (int v = 1; v < 5; ++v) {
        float* o = mats + (v-1)*12;
        for (int r = 0; r < 3; ++r) {
            for (int c = 0; c < 3; ++c) {
                double s = 0.0;
                for (int k = 0; k < 3; ++k) s += F[v][r*4+k]*inv[k*3+c];
                o[r*3+c] = (float)s;
            }
            double tr = F[v][r*4+3] + F[v][r*4+0]*it[0]
                      + F[v][r*4+1]*it[1] + F[v][r*4+2]*it[2];
            o[9+r] = (float)tr;
        }
    }
}

// ---------------------------------------------------------------- transpose (C,H,W) -> (HW, C), all 5 views
__global__ void k_transpose(const float* __restrict__ f0, const float* __restrict__ f1,
                            const float* __restrict__ f2, const float* __restrict__ f3,
                            const float* __restrict__ f4, float* __restrict__ ft)
{
    const int bv = blockIdx.y;
    const float* f = (bv==0) ? f0 : (bv==1) ? f1 : (bv==2) ? f2 : (bv==3) ? f3 : f4;
    float* o = ft + (size_t)bv * (HW_*C_);
    __shared__ float tile[C_][65];
    const int pix0 = blockIdx.x * 64;
    const int tid = threadIdx.x;
    const int p  = tid & 63;
    const int ci = (tid >> 6) * 8;
#pragma unroll
    for (int i = 0; i < 8; ++i)
        tile[ci + i][p] = f[(size_t)(ci + i)*HW_ + pix0 + p];
    __syncthreads();
    const int c2 = tid & 31, pg = tid >> 5;
#pragma unroll
    for (int i = 0; i < 8; ++i) {
        int p2 = pg + i*8;
        o[(size_t)(pix0 + p2)*C_ + c2] = tile[c2][p2];
    }
}

// ---------------------------------------------------------------- variance slice + spatial conv
__global__ __launch_bounds__(256, 3) void k_var_conv(
    const float* __restrict__ featT, const float* __restrict__ mats,
    const float* __restrict__ depthv, const float* __restrict__ cw2,
    float* __restrict__ A)
{
    __shared__ float vlds[NP_ * C_];   // swizzled [p][c], 41.5 KB
    const int tid = threadIdx.x;
    const int x0 = blockIdx.x * TX;
    const int y0 = blockIdx.y * TY;
    const int bd = blockIdx.z;
    const float depth = depthv[bd];

    // fold depth: pxyz_i = cf[i0]*gx + cf[i1]*gy + cf[i2]
    float cf[4][9];
#pragma unroll
    for (int v = 0; v < 4; ++v) {
        const float* mm = mats + v*12;
#pragma unroll
        for (int r = 0; r < 3; ++r) {
            cf[v][r*3+0] = mm[r*3+0]*depth;
            cf[v][r*3+1] = mm[r*3+1]*depth;
            cf[v][r*3+2] = fmaf(mm[r*3+2], depth, mm[9+r]);
        }
    }

    // ------- phase 1: one halo position per thread, geometry computed once
    for (int p = tid; p < NP_; p += 256) {
        const int hy = p / HS;
        const int hx = p - hy*HS;
        const int gy = y0 - 1 + hy;
        const int gx = x0 - 1 + hx;
        const bool inimg = ((unsigned)gy < 128u) && ((unsigned)gx < 160u);
        const float vp = inimg ? 1.f : 0.f;
        const float fgx = (float)gx, fgy = (float)gy;
        const int gyc = min(max(gy, 0), H_-1);
        const int gxc = min(max(gx, 0), W_-1);
        const int refoff = (gyc*W_ + gxc)*C_;

        float wgt[4][4];
        int   off[4][4];
#pragma unroll
        for (int v = 0; v < 4; ++v) {
            const float xx = fmaf(cf[v][0],fgx, fmaf(cf[v][1],fgy, cf[v][2]));
            const float yy = fmaf(cf[v][3],fgx, fmaf(cf[v][4],fgy, cf[v][5]));
            const float zz = fmaf(cf[v][6],fgx, fmaf(cf[v][7],fgy, cf[v][8]));
            const float rz = __builtin_amdgcn_rcpf(zz);
            const float px = xx*rz, py = yy*rz;
            const float xf = floorf(px), yf = floorf(py);
            const float wx = px - xf, wy = py - yf;
            const int xi = (int)xf, yi = (int)yf;
            const bool vx0 = (xi >=  0) & (xi <= W_-1);
            const bool vx1 = (xi >= -1) & (xi <= W_-2);
            const bool vy0 = (yi >=  0) & (yi <= H_-1);
            const bool vy1 = (yi >= -1) & (yi <= H_-2);
            const int xc0 = min(max(xi,   0), W_-1);
            const int xc1 = min(max(xi+1, 0), W_-1);
            const int yr0 = min(max(yi,   0), H_-1) * W_;
            const int yr1 = min(max(yi+1, 0), H_-1) * W_;
            const float ux = 1.f - wx, uy = 1.f - wy;
            wgt[v][0] = (inimg && vx0 && vy0) ? ux*uy : 0.f;
            wgt[v][1] = (inimg && vx1 && vy0) ? wx*uy : 0.f;
            wgt[v][2] = (inimg && vx0 && vy1) ? ux*wy : 0.f;
            wgt[v][3] = (inimg && vx1 && vy1) ? wx*wy : 0.f;
            off[v][0] = (yr0 + xc0)*C_;
            off[v][1] = (yr0 + xc1)*C_;
            off[v][2] = (yr1 + xc0)*C_;
            off[v][3] = (yr1 + xc1)*C_;
        }

        const int sw = p & 7;
        float* vout = vlds + p*C_;
#pragma unroll
        for (int cp = 0; cp < 4; ++cp) {              // 8 channels per step
            const int c0 = cp*8;
            float s0[4], q0[4], s1[4], q1[4];
            {
                const float4 t0 = *reinterpret_cast<const float4*>(featT + refoff + c0);
                const float4 t1 = *reinterpret_cast<const float4*>(featT + refoff + c0 + 4);
                const float t0a[4] = {t0.x,t0.y,t0.z,t0.w};
                const float t1a[4] = {t1.x,t1.y,t1.z,t1.w};
#pragma unroll
                for (int k = 0; k < 4; ++k) {
                    s0[k] = t0a[k]*vp;  q0[k] = s0[k]*t0a[k];
                    s1[k] = t1a[k]*vp;  q1[k] = s1[k]*t1a[k];
                }
            }
#pragma unroll
            for (int v = 0; v < 4; ++v) {
                const float* fb = featT + (size_t)(v+1)*(HW_*C_) + c0;
                float4 a0c[4], a1c[4];
#pragma unroll
                for (int c4 = 0; c4 < 4; ++c4) {
                    a0c[c4] = *reinterpret_cast<const float4*>(fb + off[v][c4]);
                    a1c[c4] = *reinterpret_cast<const float4*>(fb + off[v][c4] + 4);
                }
                const float w0 = wgt[v][0], w1 = wgt[v][1], w2 = wgt[v][2], w3 = wgt[v][3];
                const float a00[4]={a0c[0].x,a0c[0].y,a0c[0].z,a0c[0].w};
                const float a10[4]={a0c[1].x,a0c[1].y,a0c[1].z,a0c[1].w};
                const float a01[4]={a0c[2].x,a0c[2].y,a0c[2].z,a0c[2].w};
                const float a11[4]={a0c[3].x,a0c[3].y,a0c[3].z,a0c[3].w};
                const float b00[4]={a1c[0].x,a1c[0].y,a1c[0].z,a1c[0].w};
                const float b10[4]={a1c[1].x,a1c[1].y,a1c[1].z,a1c[1].w};
                const float b01[4]={a1c[2].x,a1c[2].y,a1c[2].z,a1c[2].w};
                const float b11[4]={a1c[3].x,a1c[3].y,a1c[3].z,a1c[3].w};
#pragma unroll
                for (int k = 0; k < 4; ++k) {
                    const float wv0 = fmaf(a00[k],w0, fmaf(a10[k],w1, fmaf(a01[k],w2, a11[k]*w3)));
                    s0[k] += wv0;  q0[k] = fmaf(wv0, wv0, q0[k]);
                    const float wv1 = fmaf(b00[k],w0, fmaf(b10[k],w1, fmaf(b01[k],w2, b11[k]*w3)));
                    s1[k] += wv1;  q1[k] = fmaf(wv1, wv1, q1[k]);
                }
            }
            float o0[4], o1[4];
#pragma unroll
            for (int k = 0; k < 4; ++k) {
                const float m0 = s0[k]*0.2f;  o0[k] = q0[k]*0.2f - m0*m0;
                const float m1 = s1[k]*0.2f;  o1[k] = q1[k]*0.2f - m1*m1;
            }
            *reinterpret_cast<float4*>(vout + (((2*cp  )^sw)<<2)) = make_float4(o0[0],o0[1],o0[2],o0[3]);
            *reinterpret_cast<float4*>(vout + (((2*cp+1)^sw)<<2)) = make_float4(o1[0],o1[1],o1[2],o1[3]);
        }
    }
    __syncthreads();

    // ------- phase 2: 3x3 spatial conv, 3 depth-tap partials
    const int oy = tid >> 4;
    const int ox = tid & 15;
    float acc0 = 0.f, acc1 = 0.f, acc2 = 0.f;
#pragma unroll
    for (int ky = 0; ky < 3; ++ky) {
#pragma unroll
        for (int kx = 0; kx < 3; ++kx) {
            const int p = (oy+ky)*HS + (ox+kx);
            const int sw = p & 7;
            const float* wt   = cw2 + (ky*3+kx)*96;   // [c][kd] contiguous
            const float* vrow = vlds + p*C_;
#pragma unroll
            for (int cq = 0; cq < 8; ++cq) {
                const float4 dv = *reinterpret_cast<const float4*>(vrow + ((cq^sw)<<2));
                const float da[4] = {dv.x,dv.y,dv.z,dv.w};
#pragma unroll
                for (int k = 0; k < 4; ++k) {
                    const float* wc = wt + (cq*4+k)*3;
                    acc0 = fmaf(da[k], wc[0], acc0);
                    acc1 = fmaf(da[k], wc[1], acc1);
                    acc2 = fmaf(da[k], wc[2], acc2);
                }
            }
        }
    }
    const size_t o = (size_t)bd*HW_ + (size_t)(y0+oy)*W_ + (x0+ox);
    A[o]                    = acc0;
    A[(size_t)DHW_ + o]     = acc1;
    A[2*(size_t)DHW_ + o]   = acc2;
}

// ---------------------------------------------------------------- depth combine + softmax
__global__ void k_softmax(const float* __restrict__ A,
                          const float* __restrict__ conv_b,
                          float* __restrict__ out)
{
    const int pix = blockIdx.x*256 + threadIdx.x;
    const float bs = conv_b[0];
    float cst[D_];
#pragma unroll
    for (int d = 0; d < D_; ++d) {
        float v = A[(size_t)DHW_ + (size_t)d*HW_ + pix];                  // A1[d]
        if (d > 0)      v += A[(size_t)(d-1)*HW_ + pix];                  // A0[d-1]
        if (d < D_-1)   v += A[2*(size_t)DHW_ + (size_t)(d+1)*HW_ + pix]; // A2[d+1]
        cst[d] = v + bs;
    }
    float m = cst[0];
#pragma unroll
    for (int d = 1; d < D_; ++d) m = fmaxf(m, cst[d]);
    float s = 0.f;
#pragma unroll
    for (int d = 0; d < D_; ++d) { cst[d] = expf(cst[d] - m); s += cst[d]; }
    const float rs = 1.0f / s;
#pragma unroll
    for (int d = 0; d < D_; ++d)
        out[(size_t)d*HW_ + pix] = cst[d]*rs;
}

// ---------------------------------------------------------------- launch
extern "C" void kernel_launch(void* const* d_in, const int* in_sizes, int n_in,
                              void* d_out, int out_size, void* d_ws, size_t ws_size,
                              hipStream_t stream)
{
    const float* proj   = (const float*)d_in[5];
    const float* depth  = (const float*)d_in[6];
    const float* conv_w = (const float*)d_in[8];
    const float* conv_b = (const float*)d_in[9];

    float* ws    = (float*)d_ws;
    float* featT = ws;
    float* mats  = ws + MATS_OFF;
    float* cw2   = ws + CW2_OFF;
    float* A     = ws + A_OFF;

    k_setup<<<1, 64, 0, stream>>>(proj, conv_w, mats, cw2);
    dim3 gt(HW_/64, 5);
    k_transpose<<<gt, 256, 0, stream>>>((const float*)d_in[0], (const float*)d_in[1],
                                        (const float*)d_in[2], (const float*)d_in[3],
                                        (const float*)d_in[4], featT);
    dim3 g1(W_/TX, H_/TY, D_);   // (10, 8, 64)
    k_var_conv<<<g1, 256, 0, stream>>>(featT, mats, depth, cw2, A);
    k_softmax<<<HW_/256, 256, 0, stream>>>(A, conv_b, (float*)d_out);
}

// Round 3
// 212.720 us; speedup vs baseline: 3.6384x; 3.6384x over previous
//
#include <hip/hip_runtime.h>

#define H_ 128
#define W_ 160
#define C_ 32
#define D_ 64
#define HW_ (H_*W_)          // 20480
#define DHW_ (D_*HW_)        // 1310720

// var/conv tile
#define TY 16
#define TX 16
#define HS 18                // halo side
#define NP_ (HS*HS)          // 324

// geo LDS layout: stride 28 dwords per position
//  [0..15]  wgt[v][k]  (4x float4, 16B aligned)
//  [16..23] {offb00,dpack} per view (4x int2, 8B aligned)
//  [24..25] {refoffb, vp}
#define GSTR 28

// ws layout (floats)
#define FEATT_SZ (5*HW_*C_)          // 3,276,800
#define MATS_OFF FEATT_SZ
#define CW3_OFF (MATS_OFF + 64)
#define A_OFF (CW3_OFF + 1152)

// ---- packed fp32 helpers (v_pk_* are CDNA VOP3P, present on gfx950)
using v2f = __attribute__((ext_vector_type(2))) float;

__device__ __forceinline__ v2f pk_mul(v2f a, v2f b) {
    v2f d; asm("v_pk_mul_f32 %0, %1, %2" : "=v"(d) : "v"(a), "v"(b)); return d;
}
__device__ __forceinline__ v2f pk_add(v2f a, v2f b) {
    v2f d; asm("v_pk_add_f32 %0, %1, %2" : "=v"(d) : "v"(a), "v"(b)); return d;
}
__device__ __forceinline__ v2f pk_fma(v2f a, v2f b, v2f c) {
    v2f d; asm("v_pk_fma_f32 %0, %1, %2, %3" : "=v"(d) : "v"(a), "v"(b), "v"(c)); return d;
}
// src1 broadcast lo / hi
__device__ __forceinline__ v2f pk_mul_blo(v2f a, v2f b) {
    v2f d; asm("v_pk_mul_f32 %0, %1, %2 op_sel:[0,0] op_sel_hi:[1,0]" : "=v"(d) : "v"(a), "v"(b)); return d;
}
__device__ __forceinline__ v2f pk_mul_bhi(v2f a, v2f b) {
    v2f d; asm("v_pk_mul_f32 %0, %1, %2 op_sel:[0,1] op_sel_hi:[1,1]" : "=v"(d) : "v"(a), "v"(b)); return d;
}
__device__ __forceinline__ v2f pk_fma_blo(v2f a, v2f b, v2f c) {
    v2f d; asm("v_pk_fma_f32 %0, %1, %2, %3 op_sel:[0,0,0] op_sel_hi:[1,0,1]" : "=v"(d) : "v"(a), "v"(b), "v"(c)); return d;
}
__device__ __forceinline__ v2f pk_fma_bhi(v2f a, v2f b, v2f c) {
    v2f d; asm("v_pk_fma_f32 %0, %1, %2, %3 op_sel:[0,1,0] op_sel_hi:[1,1,1]" : "=v"(d) : "v"(a), "v"(b), "v"(c)); return d;
}
// src0 broadcast lo / hi
__device__ __forceinline__ v2f pk_fma_alo(v2f a, v2f b, v2f c) {
    v2f d; asm("v_pk_fma_f32 %0, %1, %2, %3 op_sel:[0,0,0] op_sel_hi:[0,1,1]" : "=v"(d) : "v"(a), "v"(b), "v"(c)); return d;
}
__device__ __forceinline__ v2f pk_fma_ahi(v2f a, v2f b, v2f c) {
    v2f d; asm("v_pk_fma_f32 %0, %1, %2, %3 op_sel:[1,0,0] op_sel_hi:[1,1,1]" : "=v"(d) : "v"(a), "v"(b), "v"(c)); return d;
}
// d = (-a)*a + c
__device__ __forceinline__ v2f pk_fma_nsq(v2f a, v2f c) {
    v2f d; asm("v_pk_fma_f32 %0, %1, %1, %2 neg_lo:[1,0,0] neg_hi:[1,0,0]" : "=v"(d) : "v"(a), "v"(c)); return d;
}

// ---------------------------------------------------------------- setup: mats + weight rearrange
__global__ void k_setup(const float* __restrict__ proj,
                        const float* __restrict__ convw,
                        float* __restrict__ mats,
                        float* __restrict__ cw3)
{
    const int tid = threadIdx.x;
    // cw3[tap][c][kd(pad4)] <- convw[c][kd][ky][kx]
    for (int o = tid; o < 1152; o += 64) {
        const int tap = o >> 7;
        const int r   = o & 127;
        const int c   = r >> 2;
        const int kd  = r & 3;
        cw3[o] = (kd < 3) ? convw[c*27 + kd*9 + tap] : 0.f;
    }
    if (tid != 0) return;
    double F[5][12];
    for (int v = 0; v < 5; ++v) {
        const float* E = proj + v*32;
        const float* K = proj + v*32 + 16;
        for (int i = 0; i < 3; ++i)
            for (int j = 0; j < 4; ++j) {
                double s = 0.0;
                for (int k = 0; k < 3; ++k)
                    s += (double)K[i*4+k] * (double)E[k*4+j];
                F[v][i*4+j] = s;
            }
    }
    const double m00=F[0][0], m01=F[0][1], m02=F[0][2],  t0x=F[0][3];
    const double m10=F[0][4], m11=F[0][5], m12=F[0][6],  t0y=F[0][7];
    const double m20=F[0][8], m21=F[0][9], m22=F[0][10], t0z=F[0][11];
    const double det = m00*(m11*m22-m12*m21) - m01*(m10*m22-m12*m20)
                     + m02*(m10*m21-m11*m20);
    const double id = 1.0/det;
    double inv[9];
    inv[0] = (m11*m22-m12*m21)*id; inv[1] = (m02*m21-m01*m22)*id; inv[2] = (m01*m12-m02*m11)*id;
    inv[3] = (m12*m20-m10*m22)*id; inv[4] = (m00*m22-m02*m20)*id; inv[5] = (m02*m10-m00*m12)*id;
    inv[6] = (m10*m21-m11*m20)*id; inv[7] = (m01*m20-m00*m21)*id; inv[8] = (m00*m11-m01*m10)*id;
    double it[3];
    it[0] = -(inv[0]*t0x + inv[1]*t0y + inv[2]*t0z);
    it[1] = -(inv[3]*t0x + inv[4]*t0y + inv[5]*t0z);
    it[2] = -(inv[6]*t0x + inv[7]*t0y + inv[8]*t0z);
    for (int v = 1; v < 5; ++v) {
        float* o = mats + (v-1)*12;
        for (int r = 0; r < 3; ++r) {
            for (int c = 0; c < 3; ++c) {
                double s = 0.0;
                for (int k = 0; k < 3; ++k) s += F[v][r*4+k]*inv[k*3+c];
                o[r*3+c] = (float)s;
            }
            double tr = F[v][r*4+3] + F[v][r*4+0]*it[0]
                      + F[v][r*4+1]*it[1] + F[v][r*4+2]*it[2];
            o[9+r] = (float)tr;
        }
    }
}

// ---------------------------------------------------------------- transpose (C,H,W) -> (HW, C), all 5 views
__global__ void k_transpose(const float* __restrict__ f0, const float* __restrict__ f1,
                            const float* __restrict__ f2, const float* __restrict__ f3,
                            const float* __restrict__ f4, float* __restrict__ ft)
{
    const int bv = blockIdx.y;
    const float* f = (bv==0) ? f0 : (bv==1) ? f1 : (bv==2) ? f2 : (bv==3) ? f3 : f4;
    float* o = ft + (size_t)bv * (HW_*C_);
    __shared__ float tile[C_][65];
    const int pix0 = blockIdx.x * 64;
    const int tid = threadIdx.x;
    const int p  = tid & 63;
    const int ci = (tid >> 6) * 8;
#pragma unroll
    for (int i = 0; i < 8; ++i)
        tile[ci + i][p] = f[(size_t)(ci + i)*HW_ + pix0 + p];
    __syncthreads();
    const int c2 = tid & 31, pg = tid >> 5;
#pragma unroll
    for (int i = 0; i < 8; ++i) {
        int p2 = pg + i*8;
        o[(size_t)(pix0 + p2)*C_ + c2] = tile[c2][p2];
    }
}

// ---------------------------------------------------------------- variance slice + spatial conv
__global__ __launch_bounds__(256, 2) void k_var_conv(
    const float* __restrict__ featT, const float* __restrict__ mats,
    const float* __restrict__ depthv, const float* __restrict__ cw3,
    float* __restrict__ A)
{
    __shared__ float geo[NP_ * GSTR];   // 36.3 KB
    __shared__ float vlds[NP_ * C_];    // 41.5 KB
    const int tid = threadIdx.x;
    const int x0 = blockIdx.x * TX;
    const int y0 = blockIdx.y * TY;
    const int bd = blockIdx.z;
    const float depth = depthv[bd];

    // ---- phase 0: geometry, one position per thread (math only)
    {
        float cf[4][9];
#pragma unroll
        for (int v = 0; v < 4; ++v) {
            const float* mm = mats + v*12;
#pragma unroll
            for (int r = 0; r < 3; ++r) {
                cf[v][r*3+0] = mm[r*3+0]*depth;
                cf[v][r*3+1] = mm[r*3+1]*depth;
                cf[v][r*3+2] = fmaf(mm[r*3+2], depth, mm[9+r]);
            }
        }
        for (int p = tid; p < NP_; p += 256) {
            const int hy = p / HS;
            const int hx = p - hy*HS;
            const int gy = y0 - 1 + hy;
            const int gx = x0 - 1 + hx;
            const bool inimg = ((unsigned)gy < 128u) && ((unsigned)gx < 160u);
            const float vp = inimg ? 1.f : 0.f;
            const float fgx = (float)gx, fgy = (float)gy;
            const int gyc = min(max(gy, 0), H_-1);
            const int gxc = min(max(gx, 0), W_-1);
            const int refoffb = (gyc*W_ + gxc) << 7;   // *32ch*4B
            float* gp = geo + p*GSTR;
#pragma unroll
            for (int v = 0; v < 4; ++v) {
                const float xx = fmaf(cf[v][0],fgx, fmaf(cf[v][1],fgy, cf[v][2]));
                const float yy = fmaf(cf[v][3],fgx, fmaf(cf[v][4],fgy, cf[v][5]));
                const float zz = fmaf(cf[v][6],fgx, fmaf(cf[v][7],fgy, cf[v][8]));
                const float rz = __builtin_amdgcn_rcpf(zz);
                const float px = xx*rz, py = yy*rz;
                const float xf = floorf(px), yf = floorf(py);
                const float wx = px - xf, wy = py - yf;
                const int xi = (int)xf, yi = (int)yf;
                const bool vx0 = (xi >=  0) & (xi <= W_-1);
                const bool vx1 = (xi >= -1) & (xi <= W_-2);
                const bool vy0 = (yi >=  0) & (yi <= H_-1);
                const bool vy1 = (yi >= -1) & (yi <= H_-2);
                const int xc0 = min(max(xi,   0), W_-1);
                const int xc1 = min(max(xi+1, 0), W_-1);
                const int yc0 = min(max(yi,   0), H_-1);
                const int yc1 = min(max(yi+1, 0), H_-1);
                const float ux = 1.f - wx, uy = 1.f - wy;
                float4 w4;
                w4.x = (inimg && vx0 && vy0) ? ux*uy : 0.f;
                w4.y = (inimg && vx1 && vy0) ? wx*uy : 0.f;
                w4.z = (inimg && vx0 && vy1) ? ux*wy : 0.f;
                w4.w = (inimg && vx1 && vy1) ? wx*wy : 0.f;
                const int offb00 = (yc0*W_ + xc0) << 7;
                const int dxb    = (xc1 - xc0) << 7;        // 0 or 128
                const int dyb    = (yc1 - yc0) << 7+6;      // careful below
                // dy bytes = (yc1-yc0)*W_*C_*4 = (yc1-yc0)*20480
                const int dyb2   = (yc1 - yc0) * 20480;
                (void)dyb;
                *reinterpret_cast<float4*>(gp + v*4) = w4;
                int2 oo; oo.x = offb00; oo.y = dxb | dyb2;
                *reinterpret_cast<int2*>(gp + 16 + v*2) = oo;
            }
            float2 misc; misc.x = __int_as_float(refoffb); misc.y = vp;
            *reinterpret_cast<float2*>(gp + 24) = misc;
        }
    }
    __syncthreads();

    // ---- phase 1: gathers + variance (8 lanes per position, quad channels each)
    {
        const int q = tid & 7;
        const int lane_cb = q << 4;        // channel-quad byte offset
        const int pg = tid >> 3;
        const char* fT = (const char*)featT;

        for (int p = pg; p < NP_; p += 32) {
            const float* gp = geo + p*GSTR;
            const float2 misc = *reinterpret_cast<const float2*>(gp + 24);
            v2f misc2 = { misc.x, misc.y };
            const int refoffb = __float_as_int(misc.x) + lane_cb;

            const float4 tr = *reinterpret_cast<const float4*>(fT + refoffb);
            v2f tlo = { tr.x, tr.y }, thi = { tr.z, tr.w };
            v2f s01 = pk_mul_bhi(tlo, misc2);   // f * vp
            v2f s23 = pk_mul_bhi(thi, misc2);
            v2f q01 = pk_mul(s01, tlo);         // f^2 * vp
            v2f q23 = pk_mul(s23, thi);

#pragma unroll
            for (int v = 0; v < 4; ++v) {
                const float4 w4 = *reinterpret_cast<const float4*>(gp + v*4);
                const int2  oo = *reinterpret_cast<const int2*>(gp + 16 + v*2);
                const int v00 = oo.x + lane_cb;
                const int dx  = oo.y & 128;
                const int dy  = oo.y - dx;
                const char* fb = fT + (size_t)(v+1)*(HW_*C_*4);
                const float4 t00 = *reinterpret_cast<const float4*>(fb + v00);
                const float4 t10 = *reinterpret_cast<const float4*>(fb + (v00 + dx));
                const float4 t01 = *reinterpret_cast<const float4*>(fb + (v00 + dy));
                const float4 t11 = *reinterpret_cast<const float4*>(fb + (v00 + dx + dy));
                v2f w01 = { w4.x, w4.y }, w23 = { w4.z, w4.w };
                v2f a;
                a = pk_mul_blo((v2f){t00.x,t00.y}, w01);
                a = pk_fma_bhi((v2f){t10.x,t10.y}, w01, a);
                a = pk_fma_blo((v2f){t01.x,t01.y}, w23, a);
                a = pk_fma_bhi((v2f){t11.x,t11.y}, w23, a);
                s01 = pk_add(s01, a);
                q01 = pk_fma(a, a, q01);
                v2f b;
                b = pk_mul_blo((v2f){t00.z,t00.w}, w01);
                b = pk_fma_bhi((v2f){t10.z,t10.w}, w01, b);
                b = pk_fma_blo((v2f){t01.z,t01.w}, w23, b);
                b = pk_fma_bhi((v2f){t11.z,t11.w}, w23, b);
                s23 = pk_add(s23, b);
                q23 = pk_fma(b, b, q23);
            }
            const v2f c5 = { 0.2f, 0.2f };
            v2f m01 = pk_mul(s01, c5), m23 = pk_mul(s23, c5);
            v2f o01 = pk_fma_nsq(m01, pk_mul(q01, c5));
            v2f o23 = pk_fma_nsq(m23, pk_mul(q23, c5));
            float4 ov = make_float4(o01.x, o01.y, o23.x, o23.y);
            *reinterpret_cast<float4*>(vlds + p*C_ + ((q ^ (p & 7)) << 2)) = ov;
        }
    }
    __syncthreads();

    // ---- phase 2: 3x3 spatial conv, 3 depth-tap partials (packed kd0/kd1)
    const int oy = tid >> 4;
    const int ox = tid & 15;
    v2f acc01 = { 0.f, 0.f };
    float acc2 = 0.f;
#pragma unroll
    for (int ky = 0; ky < 3; ++ky) {
#pragma unroll
        for (int kx = 0; kx < 3; ++kx) {
            const int p = (oy+ky)*HS + (ox+kx);
            const int sw = p & 7;
            const float* wt   = cw3 + (ky*3+kx)*128;
            const float* vrow = vlds + p*C_;
#pragma unroll
            for (int cq = 0; cq < 8; ++cq) {
                const float4 dv = *reinterpret_cast<const float4*>(vrow + ((cq^sw)<<2));
                const float* wc = wt + cq*16;
                v2f d01 = { dv.x, dv.y }, d23 = { dv.z, dv.w };
                const float2 wk0 = *reinterpret_cast<const float2*>(wc + 0);
                const float2 wk1 = *reinterpret_cast<const float2*>(wc + 4);
                const float2 wk2 = *reinterpret_cast<const float2*>(wc + 8);
                const float2 wk3 = *reinterpret_cast<const float2*>(wc + 12);
                acc01 = pk_fma_alo(d01, (v2f){wk0.x, wk0.y}, acc01);
                acc01 = pk_fma_ahi(d01, (v2f){wk1.x, wk1.y}, acc01);
                acc01 = pk_fma_alo(d23, (v2f){wk2.x, wk2.y}, acc01);
                acc01 = pk_fma_ahi(d23, (v2f){wk3.x, wk3.y}, acc01);
                acc2 = fmaf(dv.x, wc[2],  acc2);
                acc2 = fmaf(dv.y, wc[6],  acc2);
                acc2 = fmaf(dv.z, wc[10], acc2);
                acc2 = fmaf(dv.w, wc[14], acc2);
            }
        }
    }
    const size_t o = (size_t)bd*HW_ + (size_t)(y0+oy)*W_ + (x0+ox);
    A[o]                    = acc01.x;
    A[(size_t)DHW_ + o]     = acc01.y;
    A[2*(size_t)DHW_ + o]   = acc2;
}

// ---------------------------------------------------------------- depth combine + softmax
__global__ void k_softmax(const float* __restrict__ A,
                          const float* __restrict__ conv_b,
                          float* __restrict__ out)
{
    const int pix = blockIdx.x*256 + threadIdx.x;
    const float bs = conv_b[0];
    float cst[D_];
#pragma unroll
    for (int d = 0; d < D_; ++d) {
        float v = A[(size_t)DHW_ + (size_t)d*HW_ + pix];                  // A1[d]
        if (d > 0)      v += A[(size_t)(d-1)*HW_ + pix];                  // A0[d-1]
        if (d < D_-1)   v += A[2*(size_t)DHW_ + (size_t)(d+1)*HW_ + pix]; // A2[d+1]
        cst[d] = v + bs;
    }
    float m = cst[0];
#pragma unroll
    for (int d = 1; d < D_; ++d) m = fmaxf(m, cst[d]);
    float s = 0.f;
#pragma unroll
    for (int d = 0; d < D_; ++d) { cst[d] = expf(cst[d] - m); s += cst[d]; }
    const float rs = 1.0f / s;
#pragma unroll
    for (int d = 0; d < D_; ++d)
        out[(size_t)d*HW_ + pix] = cst[d]*rs;
}

// ---------------------------------------------------------------- launch
extern "C" void kernel_launch(void* const* d_in, const int* in_sizes, int n_in,
                              void* d_out, int out_size, void* d_ws, size_t ws_size,
                              hipStream_t stream)
{
    const float* proj   = (const float*)d_in[5];
    const float* depth  = (const float*)d_in[6];
    const float* conv_w = (const float*)d_in[8];
    const float* conv_b = (const float*)d_in[9];

    float* ws    = (float*)d_ws;
    float* featT = ws;
    float* mats  = ws + MATS_OFF;
    float* cw3   = ws + CW3_OFF;
    float* A     = ws + A_OFF;

    k_setup<<<1, 64, 0, stream>>>(proj, conv_w, mats, cw3);
    dim3 gt(HW_/64, 5);
    k_transpose<<<gt, 256, 0, stream>>>((const float*)d_in[0], (const float*)d_in[1],
                                        (const float*)d_in[2], (const float*)d_in[3],
                                        (const float*)d_in[4], featT);
    dim3 g1(W_/TX, H_/TY, D_);   // (10, 8, 64)
    k_var_conv<<<g1, 256, 0, stream>>>(featT, mats, depth, cw3, A);
    k_softmax<<<HW_/256, 256, 0, stream>>>(A, conv_b, (float*)d_out);
}

// Round 4
// 207.713 us; speedup vs baseline: 3.7261x; 1.0241x over previous
//
#include <hip/hip_runtime.h>

#define H_ 128
#define W_ 160
#define C_ 32
#define D_ 64
#define HW_ (H_*W_)          // 20480
#define DHW_ (D_*HW_)        // 1310720

// var/conv tile
#define TY 16
#define TX 16
#define HS 18                // halo side
#define NP_ (HS*HS)          // 324
#define PCHUNK 81            // positions per geo chunk (4 chunks)

// geo LDS layout: stride 28 dwords per position
//  [0..15]  wgt[v][k]  (4x float4)
//  [16..23] {offb00,dpack} per view (4x int2)
//  [24..25] {refoffb, vp}
#define GSTR 28

// ws layout (floats)
#define FEATT_SZ (5*HW_*C_)          // 3,276,800
#define MATS_OFF FEATT_SZ
#define CW3_OFF (MATS_OFF + 64)
#define A_OFF (CW3_OFF + 1152)

// ---- packed fp32 helpers (VOP3P)
using v2f = __attribute__((ext_vector_type(2))) float;

__device__ __forceinline__ v2f pk_mul(v2f a, v2f b) {
    v2f d; asm("v_pk_mul_f32 %0, %1, %2" : "=v"(d) : "v"(a), "v"(b)); return d;
}
__device__ __forceinline__ v2f pk_add(v2f a, v2f b) {
    v2f d; asm("v_pk_add_f32 %0, %1, %2" : "=v"(d) : "v"(a), "v"(b)); return d;
}
__device__ __forceinline__ v2f pk_fma(v2f a, v2f b, v2f c) {
    v2f d; asm("v_pk_fma_f32 %0, %1, %2, %3" : "=v"(d) : "v"(a), "v"(b), "v"(c)); return d;
}
__device__ __forceinline__ v2f pk_mul_blo(v2f a, v2f b) {
    v2f d; asm("v_pk_mul_f32 %0, %1, %2 op_sel:[0,0] op_sel_hi:[1,0]" : "=v"(d) : "v"(a), "v"(b)); return d;
}
__device__ __forceinline__ v2f pk_mul_bhi(v2f a, v2f b) {
    v2f d; asm("v_pk_mul_f32 %0, %1, %2 op_sel:[0,1] op_sel_hi:[1,1]" : "=v"(d) : "v"(a), "v"(b)); return d;
}
__device__ __forceinline__ v2f pk_fma_blo(v2f a, v2f b, v2f c) {
    v2f d; asm("v_pk_fma_f32 %0, %1, %2, %3 op_sel:[0,0,0] op_sel_hi:[1,0,1]" : "=v"(d) : "v"(a), "v"(b), "v"(c)); return d;
}
__device__ __forceinline__ v2f pk_fma_bhi(v2f a, v2f b, v2f c) {
    v2f d; asm("v_pk_fma_f32 %0, %1, %2, %3 op_sel:[0,1,0] op_sel_hi:[1,1,1]" : "=v"(d) : "v"(a), "v"(b), "v"(c)); return d;
}
__device__ __forceinline__ v2f pk_fma_alo(v2f a, v2f b, v2f c) {
    v2f d; asm("v_pk_fma_f32 %0, %1, %2, %3 op_sel:[0,0,0] op_sel_hi:[0,1,1]" : "=v"(d) : "v"(a), "v"(b), "v"(c)); return d;
}
__device__ __forceinline__ v2f pk_fma_ahi(v2f a, v2f b, v2f c) {
    v2f d; asm("v_pk_fma_f32 %0, %1, %2, %3 op_sel:[1,0,0] op_sel_hi:[1,1,1]" : "=v"(d) : "v"(a), "v"(b), "v"(c)); return d;
}
__device__ __forceinline__ v2f pk_fma_nsq(v2f a, v2f c) {
    v2f d; asm("v_pk_fma_f32 %0, %1, %1, %2 neg_lo:[1,0,0] neg_hi:[1,0,0]" : "=v"(d) : "v"(a), "v"(c)); return d;
}

// ---------------------------------------------------------------- setup: mats + weight rearrange
__global__ void k_setup(const float* __restrict__ proj,
                        const float* __restrict__ convw,
                        float* __restrict__ mats,
                        float* __restrict__ cw3)
{
    const int tid = threadIdx.x;
    for (int o = tid; o < 1152; o += 64) {
        const int tap = o >> 7;
        const int r   = o & 127;
        const int c   = r >> 2;
        const int kd  = r & 3;
        cw3[o] = (kd < 3) ? convw[c*27 + kd*9 + tap] : 0.f;
    }
    if (tid != 0) return;
    double F[5][12];
    for (int v = 0; v < 5; ++v) {
        const float* E = proj + v*32;
        const float* K = proj + v*32 + 16;
        for (int i = 0; i < 3; ++i)
            for (int j = 0; j < 4; ++j) {
                double s = 0.0;
                for (int k = 0; k < 3; ++k)
                    s += (double)K[i*4+k] * (double)E[k*4+j];
                F[v][i*4+j] = s;
            }
    }
    const double m00=F[0][0], m01=F[0][1], m02=F[0][2],  t0x=F[0][3];
    const double m10=F[0][4], m11=F[0][5], m12=F[0][6],  t0y=F[0][7];
    const double m20=F[0][8], m21=F[0][9], m22=F[0][10], t0z=F[0][11];
    const double det = m00*(m11*m22-m12*m21) - m01*(m10*m22-m12*m20)
                     + m02*(m10*m21-m11*m20);
    const double id = 1.0/det;
    double inv[9];
    inv[0] = (m11*m22-m12*m21)*id; inv[1] = (m02*m21-m01*m22)*id; inv[2] = (m01*m12-m02*m11)*id;
    inv[3] = (m12*m20-m10*m22)*id; inv[4] = (m00*m22-m02*m20)*id; inv[5] = (m02*m10-m00*m12)*id;
    inv[6] = (m10*m21-m11*m20)*id; inv[7] = (m01*m20-m00*m21)*id; inv[8] = (m00*m11-m01*m10)*id;
    double it[3];
    it[0] = -(inv[0]*t0x + inv[1]*t0y + inv[2]*t0z);
    it[1] = -(inv[3]*t0x + inv[4]*t0y + inv[5]*t0z);
    it[2] = -(inv[6]*t0x + inv[7]*t0y + inv[8]*t0z);
    for (int v = 1; v < 5; ++v) {
        float* o = mats + (v-1)*12;
        for (int r = 0; r < 3; ++r) {
            for (int c = 0; c < 3; ++c) {
                double s = 0.0;
                for (int k = 0; k < 3; ++k) s += F[v][r*4+k]*inv[k*3+c];
                o[r*3+c] = (float)s;
            }
            double tr = F[v][r*4+3] + F[v][r*4+0]*it[0]
                      + F[v][r*4+1]*it[1] + F[v][r*4+2]*it[2];
            o[9+r] = (float)tr;
        }
    }
}

// ---------------------------------------------------------------- transpose (C,H,W) -> (HW, C), all 5 views
__global__ void k_transpose(const float* __restrict__ f0, const float* __restrict__ f1,
                            const float* __restrict__ f2, const float* __restrict__ f3,
                            const float* __restrict__ f4, float* __restrict__ ft)
{
    const int bv = blockIdx.y;
    const float* f = (bv==0) ? f0 : (bv==1) ? f1 : (bv==2) ? f2 : (bv==3) ? f3 : f4;
    float* o = ft + (size_t)bv * (HW_*C_);
    __shared__ float tile[C_][65];
    const int pix0 = blockIdx.x * 64;
    const int tid = threadIdx.x;
    const int p  = tid & 63;
    const int ci = (tid >> 6) * 8;
#pragma unroll
    for (int i = 0; i < 8; ++i)
        tile[ci + i][p] = f[(size_t)(ci + i)*HW_ + pix0 + p];
    __syncthreads();
    const int c2 = tid & 31, pg = tid >> 5;
#pragma unroll
    for (int i = 0; i < 8; ++i) {
        int p2 = pg + i*8;
        o[(size_t)(pix0 + p2)*C_ + c2] = tile[c2][p2];
    }
}

// ---------------------------------------------------------------- variance slice + spatial conv
__global__ __launch_bounds__(256, 3) void k_var_conv(
    const float* __restrict__ featT, const float* __restrict__ mats,
    const float* __restrict__ depthv, const float* __restrict__ cw3,
    float* __restrict__ A)
{
    __shared__ float geo[PCHUNK * GSTR];   // 9.1 KB (one position-chunk)
    __shared__ float vlds[NP_ * C_];       // 41.5 KB
    const int tid = threadIdx.x;
    const int x0 = blockIdx.x * TX;
    const int y0 = blockIdx.y * TY;
    const int bd = blockIdx.z;
    const float depth = depthv[bd];

    const int q = tid & 7;
    const int lane_cb = q << 4;
    const int pg = tid >> 3;
    const char* fT = (const char*)featT;

    for (int chunk = 0; chunk < 4; ++chunk) {
        const int base = chunk * PCHUNK;

        // ---- phase 0: geometry, task = (position, view), 324 tasks over 256 threads
        for (int t = tid; t < PCHUNK*4; t += 256) {
            const int pos = t >> 2;       // 0..80 local
            const int v   = t & 3;
            const int p   = base + pos;   // absolute halo index
            const int hy = p / HS;
            const int hx = p - hy*HS;
            const int gy = y0 - 1 + hy;
            const int gx = x0 - 1 + hx;
            const bool inimg = ((unsigned)gy < 128u) && ((unsigned)gx < 160u);
            const float fgx = (float)gx, fgy = (float)gy;
            float* gp = geo + pos*GSTR;

            // per-view folded projection
            const float* mm = mats + v*12;
            const float c0 = mm[0]*depth, c1 = mm[1]*depth, c2 = fmaf(mm[2], depth, mm[9]);
            const float c3 = mm[3]*depth, c4 = mm[4]*depth, c5 = fmaf(mm[5], depth, mm[10]);
            const float c6 = mm[6]*depth, c7 = mm[7]*depth, c8 = fmaf(mm[8], depth, mm[11]);

            const float xx = fmaf(c0,fgx, fmaf(c1,fgy, c2));
            const float yy = fmaf(c3,fgx, fmaf(c4,fgy, c5));
            const float zz = fmaf(c6,fgx, fmaf(c7,fgy, c8));
            const float rz = __builtin_amdgcn_rcpf(zz);
            const float px = xx*rz, py = yy*rz;
            const float xf = floorf(px), yf = floorf(py);
            const float wx = px - xf, wy = py - yf;
            const int xi = (int)xf, yi = (int)yf;
            const bool vx0 = (xi >=  0) & (xi <= W_-1);
            const bool vx1 = (xi >= -1) & (xi <= W_-2);
            const bool vy0 = (yi >=  0) & (yi <= H_-1);
            const bool vy1 = (yi >= -1) & (yi <= H_-2);
            const int xc0 = min(max(xi,   0), W_-1);
            const int xc1 = min(max(xi+1, 0), W_-1);
            const int yc0 = min(max(yi,   0), H_-1);
            const int yc1 = min(max(yi+1, 0), H_-1);
            const float ux = 1.f - wx, uy = 1.f - wy;
            float4 w4;
            w4.x = (inimg && vx0 && vy0) ? ux*uy : 0.f;
            w4.y = (inimg && vx1 && vy0) ? wx*uy : 0.f;
            w4.z = (inimg && vx0 && vy1) ? ux*wy : 0.f;
            w4.w = (inimg && vx1 && vy1) ? wx*wy : 0.f;
            const int offb00 = (yc0*W_ + xc0) << 7;
            const int dxb    = (xc1 - xc0) << 7;         // 0 or 128
            const int dyb    = (yc1 - yc0) * 20480;      // 0 or row-bytes
            *reinterpret_cast<float4*>(gp + v*4) = w4;
            int2 oo; oo.x = offb00; oo.y = dxb | dyb;
            *reinterpret_cast<int2*>(gp + 16 + v*2) = oo;
            if (v == 0) {
                const int gyc = min(max(gy, 0), H_-1);
                const int gxc = min(max(gx, 0), W_-1);
                float2 misc;
                misc.x = __int_as_float((gyc*W_ + gxc) << 7);
                misc.y = inimg ? 1.f : 0.f;
                *reinterpret_cast<float2*>(gp + 24) = misc;
            }
        }
        __syncthreads();

        // ---- phase 1: gathers + variance (8 lanes per position)
        for (int p = pg; p < PCHUNK; p += 32) {
            const int ap = base + p;
            const float* gp = geo + p*GSTR;
            const float2 misc = *reinterpret_cast<const float2*>(gp + 24);
            v2f misc2 = { misc.x, misc.y };
            const int refoffb = __float_as_int(misc.x) + lane_cb;

            const float4 tr = *reinterpret_cast<const float4*>(fT + refoffb);
            v2f tlo = { tr.x, tr.y }, thi = { tr.z, tr.w };
            v2f s01 = pk_mul_bhi(tlo, misc2);   // f * vp
            v2f s23 = pk_mul_bhi(thi, misc2);
            v2f q01 = pk_mul(s01, tlo);         // f^2 * vp
            v2f q23 = pk_mul(s23, thi);

#pragma unroll
            for (int v = 0; v < 4; ++v) {
                const float4 w4 = *reinterpret_cast<const float4*>(gp + v*4);
                const int2  oo = *reinterpret_cast<const int2*>(gp + 16 + v*2);
                const int v00 = oo.x + lane_cb;
                const int dx  = oo.y & 128;
                const int dy  = oo.y - dx;
                const char* fb = fT + (size_t)(v+1)*(HW_*C_*4);
                const float4 t00 = *reinterpret_cast<const float4*>(fb + v00);
                const float4 t10 = *reinterpret_cast<const float4*>(fb + (v00 + dx));
                const float4 t01 = *reinterpret_cast<const float4*>(fb + (v00 + dy));
                const float4 t11 = *reinterpret_cast<const float4*>(fb + (v00 + dx + dy));
                v2f w01 = { w4.x, w4.y }, w23 = { w4.z, w4.w };
                v2f a;
                a = pk_mul_blo((v2f){t00.x,t00.y}, w01);
                a = pk_fma_bhi((v2f){t10.x,t10.y}, w01, a);
                a = pk_fma_blo((v2f){t01.x,t01.y}, w23, a);
                a = pk_fma_bhi((v2f){t11.x,t11.y}, w23, a);
                s01 = pk_add(s01, a);
                q01 = pk_fma(a, a, q01);
                v2f b;
                b = pk_mul_blo((v2f){t00.z,t00.w}, w01);
                b = pk_fma_bhi((v2f){t10.z,t10.w}, w01, b);
                b = pk_fma_blo((v2f){t01.z,t01.w}, w23, b);
                b = pk_fma_bhi((v2f){t11.z,t11.w}, w23, b);
                s23 = pk_add(s23, b);
                q23 = pk_fma(b, b, q23);
            }
            const v2f c5 = { 0.2f, 0.2f };
            v2f m01 = pk_mul(s01, c5), m23 = pk_mul(s23, c5);
            v2f o01 = pk_fma_nsq(m01, pk_mul(q01, c5));
            v2f o23 = pk_fma_nsq(m23, pk_mul(q23, c5));
            float4 ov = make_float4(o01.x, o01.y, o23.x, o23.y);
            *reinterpret_cast<float4*>(vlds + ap*C_ + ((q ^ (ap & 7)) << 2)) = ov;
        }
        __syncthreads();
    }

    // ---- phase 2: 3x3 spatial conv, 3 depth-tap partials (packed kd0/kd1)
    const int oy = tid >> 4;
    const int ox = tid & 15;
    v2f acc01 = { 0.f, 0.f };
    float acc2 = 0.f;
#pragma unroll
    for (int ky = 0; ky < 3; ++ky) {
#pragma unroll
        for (int kx = 0; kx < 3; ++kx) {
            const int p = (oy+ky)*HS + (ox+kx);
            const int sw = p & 7;
            const float* wt   = cw3 + (ky*3+kx)*128;
            const float* vrow = vlds + p*C_;
#pragma unroll
            for (int cq = 0; cq < 8; ++cq) {
                const float4 dv = *reinterpret_cast<const float4*>(vrow + ((cq^sw)<<2));
                const float* wc = wt + cq*16;
                v2f d01 = { dv.x, dv.y }, d23 = { dv.z, dv.w };
                const float2 wk0 = *reinterpret_cast<const float2*>(wc + 0);
                const float2 wk1 = *reinterpret_cast<const float2*>(wc + 4);
                const float2 wk2 = *reinterpret_cast<const float2*>(wc + 8);
                const float2 wk3 = *reinterpret_cast<const float2*>(wc + 12);
                acc01 = pk_fma_alo(d01, (v2f){wk0.x, wk0.y}, acc01);
                acc01 = pk_fma_ahi(d01, (v2f){wk1.x, wk1.y}, acc01);
                acc01 = pk_fma_alo(d23, (v2f){wk2.x, wk2.y}, acc01);
                acc01 = pk_fma_ahi(d23, (v2f){wk3.x, wk3.y}, acc01);
                acc2 = fmaf(dv.x, wc[2],  acc2);
                acc2 = fmaf(dv.y, wc[6],  acc2);
                acc2 = fmaf(dv.z, wc[10], acc2);
                acc2 = fmaf(dv.w, wc[14], acc2);
            }
        }
    }
    const size_t o = (size_t)bd*HW_ + (size_t)(y0+oy)*W_ + (x0+ox);
    A[o]                    = acc01.x;
    A[(size_t)DHW_ + o]     = acc01.y;
    A[2*(size_t)DHW_ + o]   = acc2;
}

// ---------------------------------------------------------------- depth combine + softmax
__global__ void k_softmax(const float* __restrict__ A,
                          const float* __restrict__ conv_b,
                          float* __restrict__ out)
{
    const int pix = blockIdx.x*256 + threadIdx.x;
    const float bs = conv_b[0];
    float cst[D_];
#pragma unroll
    for (int d = 0; d < D_; ++d) {
        float v = A[(size_t)DHW_ + (size_t)d*HW_ + pix];                  // A1[d]
        if (d > 0)      v += A[(size_t)(d-1)*HW_ + pix];                  // A0[d-1]
        if (d < D_-1)   v += A[2*(size_t)DHW_ + (size_t)(d+1)*HW_ + pix]; // A2[d+1]
        cst[d] = v + bs;
    }
    float m = cst[0];
#pragma unroll
    for (int d = 1; d < D_; ++d) m = fmaxf(m, cst[d]);
    float s = 0.f;
#pragma unroll
    for (int d = 0; d < D_; ++d) { cst[d] = expf(cst[d] - m); s += cst[d]; }
    const float rs = 1.0f / s;
#pragma unroll
    for (int d = 0; d < D_; ++d)
        out[(size_t)d*HW_ + pix] = cst[d]*rs;
}

// ---------------------------------------------------------------- launch
extern "C" void kernel_launch(void* const* d_in, const int* in_sizes, int n_in,
                              void* d_out, int out_size, void* d_ws, size_t ws_size,
                              hipStream_t stream)
{
    const float* proj   = (const float*)d_in[5];
    const float* depth  = (const float*)d_in[6];
    const float* conv_w = (const float*)d_in[8];
    const float* conv_b = (const float*)d_in[9];

    float* ws    = (float*)d_ws;
    float* featT = ws;
    float* mats  = ws + MATS_OFF;
    float* cw3   = ws + CW3_OFF;
    float* A     = ws + A_OFF;

    k_setup<<<1, 64, 0, stream>>>(proj, conv_w, mats, cw3);
    dim3 gt(HW_/64, 5);
    k_transpose<<<gt, 256, 0, stream>>>((const float*)d_in[0], (const float*)d_in[1],
                                        (const float*)d_in[2], (const float*)d_in[3],
                                        (const float*)d_in[4], featT);
    dim3 g1(W_/TX, H_/TY, D_);   // (10, 8, 64)
    k_var_conv<<<g1, 256, 0, stream>>>(featT, mats, depth, cw3, A);
    k_softmax<<<HW_/256, 256, 0, stream>>>(A, conv_b, (float*)d_out);
}